// Round 1
// baseline (1212.272 us; speedup 1.0000x reference)
//
#include <hip/hip_runtime.h>
#include <math.h>

#define BATCH 32768
#define DIM   256
#define NLAT  4096

// ---------------------------------------------------------------------------
// ws layout (float offsets):
//   [0,      32768)  float x_inv
//   [32768,  36864)  float cb_inv
//   [36864, 102400)  float bv[2][32768]   per-code-half best sim
//   [102400,167936)  int   bi[2][32768]   per-code-half best idx
//   [167936,200704)  int   best_idx[32768]
//   [200704,204800)  int   hist[4096]
//   [204800,204802)  double sse           (byte off 819200, 8-aligned)
// ---------------------------------------------------------------------------

// One wave per row: inv_norm = 1 / max(sqrt(sum(x^2)), 1e-12)
__global__ __launch_bounds__(256) void rownorm_kernel(
    const float* __restrict__ src, float* __restrict__ inv, int nrows) {
  int wave = threadIdx.x >> 6, lane = threadIdx.x & 63;
  int row = blockIdx.x * 4 + wave;
  if (row >= nrows) return;
  const float4* p = (const float4*)(src + (size_t)row * DIM);
  float4 v = p[lane];
  float s = v.x * v.x + v.y * v.y + v.z * v.z + v.w * v.w;
  #pragma unroll
  for (int off = 32; off; off >>= 1) s += __shfl_xor(s, off, 64);
  if (lane == 0) inv[row] = 1.0f / fmaxf(sqrtf(s), 1e-12f);
}

// Fused sim (x_norm . cb_norm^T) + per-row argmax over a 2048-code half.
// Block: 128 threads (tx 0..15 codes, ty 0..7 rows), 64 rows/block,
// code tile 128, d-chunk 32, 8x8 micro-tile, swizzled LDS.
#define SWZ(row, dq) ((row) * 32 + ((((dq) + ((row) >> 3)) & 7) << 2))

__global__ __launch_bounds__(128) void argmax_kernel(
    const float* __restrict__ x, const float* __restrict__ cb,
    const float* __restrict__ x_inv, const float* __restrict__ cb_inv,
    float* __restrict__ bv_out, int* __restrict__ bi_out) {
  __shared__ __align__(16) float As[64 * 32];    // 8 KB
  __shared__ __align__(16) float Bs[128 * 32];   // 16 KB

  const int tid = threadIdx.x;
  const int tx = tid & 15, ty = tid >> 4;
  const int row0 = blockIdx.x * 64;
  const int half = blockIdx.y;          // 0 or 1: codes [half*2048, +2048)
  const int ct0 = half * 16;

  float bestv[8];
  int   besti[8];
  #pragma unroll
  for (int r = 0; r < 8; ++r) { bestv[r] = -1e30f; besti[r] = 0; }

  for (int ct = ct0; ct < ct0 + 16; ++ct) {
    float acc[8][8];
    #pragma unroll
    for (int r = 0; r < 8; ++r)
      #pragma unroll
      for (int c = 0; c < 8; ++c) acc[r][c] = 0.0f;

    for (int dc = 0; dc < 8; ++dc) {          // 8 chunks of 32 dims
      __syncthreads();
      // load A chunk: 64 rows x 32 d = 512 float4, 4 per thread
      #pragma unroll
      for (int k = 0; k < 4; ++k) {
        int f = k * 128 + tid;
        int row = f >> 3, dq = f & 7;
        float inv = x_inv[row0 + row];
        float4 v = *(const float4*)(x + (size_t)(row0 + row) * DIM + dc * 32 + dq * 4);
        v.x *= inv; v.y *= inv; v.z *= inv; v.w *= inv;
        *(float4*)&As[SWZ(row, dq)] = v;
      }
      // load B chunk: 128 codes x 32 d = 1024 float4, 8 per thread
      #pragma unroll
      for (int k = 0; k < 8; ++k) {
        int f = k * 128 + tid;
        int row = f >> 3, dq = f & 7;
        int code = ct * 128 + row;
        float inv = cb_inv[code];
        float4 v = *(const float4*)(cb + (size_t)code * DIM + dc * 32 + dq * 4);
        v.x *= inv; v.y *= inv; v.z *= inv; v.w *= inv;
        *(float4*)&Bs[SWZ(row, dq)] = v;
      }
      __syncthreads();

      #pragma unroll
      for (int dq2 = 0; dq2 < 8; ++dq2) {
        float4 a[8];
        #pragma unroll
        for (int r = 0; r < 8; ++r)
          a[r] = *(float4*)&As[(ty * 8 + r) * 32 + (((dq2 + ty) & 7) << 2)];
        #pragma unroll
        for (int c = 0; c < 8; ++c) {
          float4 b = *(float4*)&Bs[(tx * 8 + c) * 32 + (((dq2 + tx) & 7) << 2)];
          #pragma unroll
          for (int r = 0; r < 8; ++r) {
            acc[r][c] = fmaf(a[r].x, b.x, acc[r][c]);
            acc[r][c] = fmaf(a[r].y, b.y, acc[r][c]);
            acc[r][c] = fmaf(a[r].z, b.z, acc[r][c]);
            acc[r][c] = fmaf(a[r].w, b.w, acc[r][c]);
          }
        }
      }
    }
    // update running argmax (ascending idx order within thread -> first wins)
    #pragma unroll
    for (int c = 0; c < 8; ++c) {
      int idx = ct * 128 + tx * 8 + c;
      #pragma unroll
      for (int r = 0; r < 8; ++r) {
        float v = acc[r][c];
        if (v > bestv[r]) { bestv[r] = v; besti[r] = idx; }
      }
    }
  }

  // cross-tx reduction via LDS (reuse As/Bs)
  __syncthreads();
  float* redv = As;          // 64*16 floats
  int*   redi = (int*)Bs;    // 64*16 ints
  #pragma unroll
  for (int r = 0; r < 8; ++r) {
    redv[(ty * 8 + r) * 16 + tx] = bestv[r];
    redi[(ty * 8 + r) * 16 + tx] = besti[r];
  }
  __syncthreads();
  if (tid < 64) {
    int row = tid;
    float bvv = redv[row * 16];
    int   bii = redi[row * 16];
    #pragma unroll
    for (int t = 1; t < 16; ++t) {
      float v = redv[row * 16 + t];
      int   i = redi[row * 16 + t];
      if (v > bvv || (v == bvv && i < bii)) { bvv = v; bii = i; }
    }
    bv_out[half * BATCH + row0 + row] = bvv;
    bi_out[half * BATCH + row0 + row] = bii;
  }
}

// Merge the two code-halves; write indices (float) and histogram.
__global__ __launch_bounds__(256) void merge_kernel(
    const float* __restrict__ bv, const int* __restrict__ bi,
    int* __restrict__ best_idx, float* __restrict__ out_idx,
    int* __restrict__ hist) {
  int row = blockIdx.x * 256 + threadIdx.x;
  float v0 = bv[row], v1 = bv[BATCH + row];
  int   i0 = bi[row], i1 = bi[BATCH + row];
  int b = (v1 > v0) ? i1 : i0;   // tie -> half0 (smaller index)
  best_idx[row] = b;
  out_idx[row] = (float)b;
  atomicAdd(&hist[b], 1);
}

// Gather z, write z_q = x + (z - x), accumulate sum((x-z)^2).
__global__ __launch_bounds__(256) void gather_kernel(
    const float* __restrict__ x, const float* __restrict__ cb,
    const int* __restrict__ best_idx, float* __restrict__ zq,
    double* __restrict__ sse) {
  int tid = threadIdx.x;
  int g = blockIdx.x * 256 + tid;          // float4 index
  int row = g >> 6, q = g & 63;
  int idx = best_idx[row];
  float4 xv = ((const float4*)x)[g];
  float4 zv = ((const float4*)cb)[idx * 64 + q];
  float4 o;
  o.x = xv.x + (zv.x - xv.x);
  o.y = xv.y + (zv.y - xv.y);
  o.z = xv.z + (zv.z - xv.z);
  o.w = xv.w + (zv.w - xv.w);
  ((float4*)zq)[g] = o;
  float dx = xv.x - zv.x, dy = xv.y - zv.y, dz = xv.z - zv.z, dw = xv.w - zv.w;
  float s = dx * dx + dy * dy + dz * dz + dw * dw;
  #pragma unroll
  for (int off = 32; off; off >>= 1) s += __shfl_xor(s, off, 64);
  __shared__ float partial[4];
  int wave = tid >> 6, lane = tid & 63;
  if (lane == 0) partial[wave] = s;
  __syncthreads();
  if (tid == 0)
    atomicAdd(sse, (double)((partial[0] + partial[1]) + (partial[2] + partial[3])));
}

// Entropy from histogram + final scalar losses.
__global__ __launch_bounds__(256) void finalize_kernel(
    const int* __restrict__ hist, const double* __restrict__ sse,
    float* __restrict__ outs) {
  int tid = threadIdx.x;
  double s = 0.0;
  for (int k = tid; k < NLAT; k += 256) {
    int c = hist[k];
    if (c > 0) {
      float p = (float)c * (1.0f / 32768.0f);
      s += (double)(p * logf(p));
    }
  }
  #pragma unroll
  for (int off = 32; off; off >>= 1) s += __shfl_xor(s, off, 64);
  __shared__ double part[4];
  int wave = tid >> 6, lane = tid & 63;
  if (lane == 0) part[wave] = s;
  __syncthreads();
  if (tid == 0) {
    double H = -((part[0] + part[1]) + (part[2] + part[3]));
    double q = sse[0] * (1.0 / ((double)BATCH * (double)DIM));
    float qf = (float)q;
    float Hf = (float)H;
    float ent_loss = -Hf;
    float vq = qf + 0.25f * qf + 0.1f * ent_loss;
    outs[0] = vq;        // vq_loss
    outs[1] = qf;        // q_loss
    outs[2] = qf;        // commit_loss (numerically identical)
    outs[3] = ent_loss;  // entropy_loss
    outs[4] = Hf;        // entropy
  }
}

extern "C" void kernel_launch(void* const* d_in, const int* in_sizes, int n_in,
                              void* d_out, int out_size, void* d_ws, size_t ws_size,
                              hipStream_t stream) {
  const float* x  = (const float*)d_in[0];
  const float* cb = (const float*)d_in[1];

  float* out      = (float*)d_out;
  float* zq       = out;                     // [0, 8388608)
  float* scalars  = out + (size_t)BATCH * DIM;          // 5 scalars
  float* out_idx  = scalars + 5;             // 32768 floats

  float* wsf      = (float*)d_ws;
  float* x_inv    = wsf;                     // 32768
  float* cb_inv   = wsf + 32768;             // 4096
  float* bv       = wsf + 36864;             // 2*32768
  int*   bi       = (int*)(wsf + 102400);    // 2*32768
  int*   best_idx = (int*)(wsf + 167936);    // 32768
  int*   hist     = (int*)(wsf + 200704);    // 4096
  double* sse     = (double*)(wsf + 204800); // byte 819200, 8-aligned

  // zero hist + sse (contiguous 16392 bytes); ws is poisoned each call
  hipMemsetAsync(hist, 0, NLAT * sizeof(int) + sizeof(double), stream);

  rownorm_kernel<<<BATCH / 4, 256, 0, stream>>>(x, x_inv, BATCH);
  rownorm_kernel<<<NLAT / 4, 256, 0, stream>>>(cb, cb_inv, NLAT);
  argmax_kernel<<<dim3(BATCH / 64, 2), 128, 0, stream>>>(x, cb, x_inv, cb_inv, bv, bi);
  merge_kernel<<<BATCH / 256, 256, 0, stream>>>(bv, bi, best_idx, out_idx, hist);
  gather_kernel<<<(BATCH * DIM / 4) / 256, 256, 0, stream>>>(x, cb, best_idx, zq, sse);
  finalize_kernel<<<1, 256, 0, stream>>>(hist, sse, scalars);
}

// Round 2
// 462.080 us; speedup vs baseline: 2.6235x; 2.6235x over previous
//
#include <hip/hip_runtime.h>
#include <math.h>

#define BATCH 32768
#define DIM   256
#define NLAT  4096

typedef _Float16 f16x8 __attribute__((ext_vector_type(8)));
typedef float    f32x16 __attribute__((ext_vector_type(16)));

// ---------------------------------------------------------------------------
// ws byte offsets
//   cbh   : fp16 normalized codebook [4096][256]            2 MB
//   cbinv : float [4096]
//   xinv  : float [32768]
//   cval  : float [32768][2][4]  per-(row,half) top-4 approx vals
//   cidx  : int   [32768][2][4]  matching code indices
//   hist  : int [4096]
//   sse   : double
// ---------------------------------------------------------------------------
#define WS_CBH    0u
#define WS_CBINV  2097152u
#define WS_XINV   2113536u
#define WS_CVAL   2244608u
#define WS_CIDX   3293184u
#define WS_HIST   4341760u
#define WS_SSE    4358144u

// One wave per codebook row: cb_inv + fp16 normalized row.
__global__ __launch_bounds__(256) void cbnorm_kernel(
    const float* __restrict__ cb, ushort* __restrict__ cbh,
    float* __restrict__ cbinv) {
  int w = threadIdx.x >> 6, l = threadIdx.x & 63;
  int row = blockIdx.x * 4 + w;
  const float4* cr = (const float4*)(cb + (size_t)row * DIM);
  float4 v = cr[l];
  float s = v.x * v.x + v.y * v.y + v.z * v.z + v.w * v.w;
  #pragma unroll
  for (int m = 32; m; m >>= 1) s += __shfl_xor(s, m, 64);
  float inv = 1.0f / fmaxf(sqrtf(s), 1e-12f);
  if (l == 0) cbinv[row] = inv;
  union { _Float16 h[4]; uint2 u; } pk;
  pk.h[0] = (_Float16)(v.x * inv);
  pk.h[1] = (_Float16)(v.y * inv);
  pk.h[2] = (_Float16)(v.z * inv);
  pk.h[3] = (_Float16)(v.w * inv);
  ((uint2*)cbh)[row * 64 + l] = pk.u;
}

// MFMA GEMM (codes x batch) + per-row top-4 candidate extraction.
// grid 256: bb = bid>>1 (256 batch rows), half = bid&1 (2048-code half).
// 4 waves, each owns 64 batch rows; x frags in registers; cbh streamed
// through 2x16KB LDS double-buffer (64 codes x 128 k per buffer).
__global__ __launch_bounds__(256, 1) void vq_gemm_kernel(
    const float* __restrict__ x, const uint4* __restrict__ cbh4,
    float* __restrict__ x_inv, float* __restrict__ cval,
    int* __restrict__ cidx) {
  __shared__ __align__(16) char smem[32768];
  char* bufs[2] = { smem, smem + 16384 };

  const int tid = threadIdx.x;
  const int w = tid >> 6, l = tid & 63;
  const int l31 = l & 31, lh = l >> 5;
  const int bb = blockIdx.x >> 1, half = blockIdx.x & 1;
  const int wrow0 = bb * 256 + w * 64;
  const int cbase = half * 2048;

  // ---- x fragments (full K=256) into registers, fused row-norm ----
  f16x8 xf[16][2];
  #pragma unroll
  for (int fc = 0; fc < 2; ++fc) {
    const int row = wrow0 + fc * 32 + l31;
    const float4* xr = (const float4*)(x + (size_t)row * DIM);
    float4 qa[16], qb[16];
    float ss = 0.f;
    #pragma unroll
    for (int s2 = 0; s2 < 16; ++s2) {
      float4 a = xr[s2 * 4 + lh * 2];
      float4 b = xr[s2 * 4 + lh * 2 + 1];
      qa[s2] = a; qb[s2] = b;
      ss += a.x * a.x + a.y * a.y + a.z * a.z + a.w * a.w
          + b.x * b.x + b.y * b.y + b.z * b.z + b.w * b.w;
    }
    ss += __shfl_xor(ss, 32, 64);
    float inv = 1.0f / fmaxf(sqrtf(ss), 1e-12f);
    if (lh == 0) x_inv[row] = inv;
    #pragma unroll
    for (int s2 = 0; s2 < 16; ++s2) {
      xf[s2][fc][0] = (_Float16)(qa[s2].x * inv);
      xf[s2][fc][1] = (_Float16)(qa[s2].y * inv);
      xf[s2][fc][2] = (_Float16)(qa[s2].z * inv);
      xf[s2][fc][3] = (_Float16)(qa[s2].w * inv);
      xf[s2][fc][4] = (_Float16)(qb[s2].x * inv);
      xf[s2][fc][5] = (_Float16)(qb[s2].y * inv);
      xf[s2][fc][6] = (_Float16)(qb[s2].z * inv);
      xf[s2][fc][7] = (_Float16)(qb[s2].w * inv);
    }
  }

  // ---- staging preamble: buf0 <- (t=0,p=0); pregs <- (t=0,p=1) ----
  uint4 pr[4];
  #pragma unroll
  for (int s = 0; s < 4; ++s) {
    int c = s * 256 + tid;
    pr[s] = cbh4[(cbase + (c >> 4)) * 32 + (c & 15)];
  }
  #pragma unroll
  for (int s = 0; s < 4; ++s) {
    int c = s * 256 + tid; int code = c >> 4; int g = c & 15;
    *(uint4*)(smem + code * 256 + ((g ^ (code & 7)) << 4)) = pr[s];
  }
  #pragma unroll
  for (int s = 0; s < 4; ++s) {
    int c = s * 256 + tid;
    pr[s] = cbh4[(cbase + (c >> 4)) * 32 + 16 + (c & 15)];
  }
  __syncthreads();

  // running top-3 per (lane, fc)
  float tv1[2] = { -3e38f, -3e38f }, tv2[2] = { -3e38f, -3e38f },
        tv3[2] = { -3e38f, -3e38f };
  int   ti1[2] = { 0, 0 }, ti2[2] = { 0, 0 }, ti3[2] = { 0, 0 };

  #pragma unroll 1
  for (int t = 0; t < 32; ++t) {
    f32x16 acc[2][2];
    #pragma unroll
    for (int rf = 0; rf < 2; ++rf)
      #pragma unroll
      for (int fc = 0; fc < 2; ++fc)
        #pragma unroll
        for (int r = 0; r < 16; ++r) acc[rf][fc][r] = 0.f;

    #pragma unroll
    for (int p = 0; p < 2; ++p) {
      // write staged data for half-tile h+1 into the other buffer
      #pragma unroll
      for (int s = 0; s < 4; ++s) {
        int c = s * 256 + tid; int code = c >> 4; int g = c & 15;
        *(uint4*)(bufs[p ^ 1] + code * 256 + ((g ^ (code & 7)) << 4)) = pr[s];
      }
      // prefetch half-tile h+2 = (t+1, p)
      int tn = (t < 31) ? (t + 1) : 31;
      #pragma unroll
      for (int s = 0; s < 4; ++s) {
        int c = s * 256 + tid;
        pr[s] = cbh4[(cbase + tn * 64 + (c >> 4)) * 32 + p * 16 + (c & 15)];
      }
      // K-loop on bufs[p] (k = 128p .. 128p+127)
      const char* bp = bufs[p];
      #pragma unroll
      for (int s = 0; s < 8; ++s) {
        f16x8 af[2];
        #pragma unroll
        for (int rf = 0; rf < 2; ++rf) {
          int m = rf * 32 + l31;
          int g = 2 * s + lh;
          af[rf] = *(const f16x8*)(bp + m * 256 + ((g ^ (m & 7)) << 4));
        }
        #pragma unroll
        for (int rf = 0; rf < 2; ++rf)
          #pragma unroll
          for (int fc = 0; fc < 2; ++fc)
            acc[rf][fc] = __builtin_amdgcn_mfma_f32_32x32x16_f16(
                af[rf], xf[p * 8 + s][fc], acc[rf][fc], 0, 0, 0);
      }
      __syncthreads();
    }

    // top-3 update for this 64-code tile
    #pragma unroll
    for (int fc = 0; fc < 2; ++fc) {
      float m = acc[0][fc][0];
      #pragma unroll
      for (int rf = 0; rf < 2; ++rf)
        #pragma unroll
        for (int r = 0; r < 16; ++r) m = fmaxf(m, acc[rf][fc][r]);
      if (m > tv3[fc]) {   // rare after early tiles
        #pragma unroll
        for (int rf = 0; rf < 2; ++rf)
          #pragma unroll
          for (int r = 0; r < 16; ++r) {
            float v = acc[rf][fc][r];
            if (v > tv3[fc]) {
              int code = cbase + t * 64 + rf * 32 + (r & 3) + 8 * (r >> 2) + 4 * lh;
              if (v > tv1[fc]) {
                tv3[fc] = tv2[fc]; ti3[fc] = ti2[fc];
                tv2[fc] = tv1[fc]; ti2[fc] = ti1[fc];
                tv1[fc] = v;       ti1[fc] = code;
              } else if (v > tv2[fc]) {
                tv3[fc] = tv2[fc]; ti3[fc] = ti2[fc];
                tv2[fc] = v;       ti2[fc] = code;
              } else {
                tv3[fc] = v;       ti3[fc] = code;
              }
            }
          }
      }
    }
  }

  // ---- merge lane pair (l, l^32) -> per-row top-4, write candidates ----
  #pragma unroll
  for (int fc = 0; fc < 2; ++fc) {
    float pv[6]; int pi[6];
    pv[0] = tv1[fc]; pv[1] = tv2[fc]; pv[2] = tv3[fc];
    pi[0] = ti1[fc]; pi[1] = ti2[fc]; pi[2] = ti3[fc];
    #pragma unroll
    for (int k = 0; k < 3; ++k) {
      pv[3 + k] = __shfl_xor(pv[k], 32, 64);
      pi[3 + k] = __shfl_xor(pi[k], 32, 64);
    }
    if (lh == 0) {
      float bv[4] = { -3e38f, -3e38f, -3e38f, -3e38f };
      int   bi[4] = { 0x7fffffff, 0x7fffffff, 0x7fffffff, 0x7fffffff };
      #pragma unroll
      for (int e = 0; e < 6; ++e) {
        float v = pv[e]; int ci = pi[e];
        #pragma unroll
        for (int k = 0; k < 4; ++k) {
          bool better = (v > bv[k]) || (v == bv[k] && ci < bi[k]);
          if (better) {
            float tv = bv[k]; int tci = bi[k];
            bv[k] = v; bi[k] = ci;
            v = tv; ci = tci;
          }
        }
      }
      int row = wrow0 + fc * 32 + l31;
      #pragma unroll
      for (int k = 0; k < 4; ++k) {
        cval[(row * 2 + half) * 4 + k] = bv[k];
        cidx[(row * 2 + half) * 4 + k] = bi[k];
      }
    }
  }
}

// Exact fp32 rescore of the 8 candidates per row + all outputs.
__global__ __launch_bounds__(256) void rescore_kernel(
    const float* __restrict__ x, const float* __restrict__ cb,
    const float* __restrict__ x_inv, const float* __restrict__ cbinv,
    const int* __restrict__ cidx, float* __restrict__ zq,
    float* __restrict__ out_idx, int* __restrict__ hist,
    double* __restrict__ sse) {
  int tid = threadIdx.x, w = tid >> 6, l = tid & 63;
  int row = blockIdx.x * 4 + w;
  const float4* xr = (const float4*)(x + (size_t)row * DIM);
  float4 xv = xr[l];
  float xinv = x_inv[row];
  float4 xn; xn.x = xv.x * xinv; xn.y = xv.y * xinv;
             xn.z = xv.z * xinv; xn.w = xv.w * xinv;
  float bestv = -3e38f; int besti = 0x7fffffff;
  for (int c = 0; c < 8; ++c) {
    int ci = cidx[row * 8 + c];
    float cbi = cbinv[ci];
    const float4* cr = (const float4*)(cb + (size_t)ci * DIM);
    float4 cv = cr[l];
    float d = xn.x * (cv.x * cbi) + xn.y * (cv.y * cbi)
            + xn.z * (cv.z * cbi) + xn.w * (cv.w * cbi);
    #pragma unroll
    for (int m = 32; m; m >>= 1) d += __shfl_xor(d, m, 64);
    bool better = (d > bestv) || (d == bestv && ci < besti);
    bestv = better ? d : bestv;
    besti = better ? ci : besti;
  }
  const float4* zr = (const float4*)(cb + (size_t)besti * DIM);
  float4 zv = zr[l];
  float4 o;
  o.x = xv.x + (zv.x - xv.x); o.y = xv.y + (zv.y - xv.y);
  o.z = xv.z + (zv.z - xv.z); o.w = xv.w + (zv.w - xv.w);
  ((float4*)(zq + (size_t)row * DIM))[l] = o;
  float dx = xv.x - zv.x, dy = xv.y - zv.y, dz = xv.z - zv.z, dw = xv.w - zv.w;
  float s = dx * dx + dy * dy + dz * dz + dw * dw;
  #pragma unroll
  for (int m = 32; m; m >>= 1) s += __shfl_xor(s, m, 64);
  __shared__ float part[4];
  if (l == 0) part[w] = s;
  __syncthreads();
  if (tid == 0)
    atomicAdd(sse, (double)((part[0] + part[1]) + (part[2] + part[3])));
  if (l == 0) {
    atomicAdd(&hist[besti], 1);
    out_idx[row] = (float)besti;
  }
}

// Entropy from histogram + final scalar losses.
__global__ __launch_bounds__(256) void finalize_kernel(
    const int* __restrict__ hist, const double* __restrict__ sse,
    float* __restrict__ outs) {
  int tid = threadIdx.x;
  double s = 0.0;
  for (int k = tid; k < NLAT; k += 256) {
    int c = hist[k];
    if (c > 0) {
      float p = (float)c * (1.0f / 32768.0f);
      s += (double)(p * logf(p));
    }
  }
  #pragma unroll
  for (int off = 32; off; off >>= 1) s += __shfl_xor(s, off, 64);
  __shared__ double part[4];
  int w = tid >> 6, l = tid & 63;
  if (l == 0) part[w] = s;
  __syncthreads();
  if (tid == 0) {
    double H = -((part[0] + part[1]) + (part[2] + part[3]));
    double q = sse[0] * (1.0 / ((double)BATCH * (double)DIM));
    float qf = (float)q;
    float Hf = (float)H;
    float ent_loss = -Hf;
    float vq = qf + 0.25f * qf + 0.1f * ent_loss;
    outs[0] = vq;
    outs[1] = qf;
    outs[2] = qf;
    outs[3] = ent_loss;
    outs[4] = Hf;
  }
}

extern "C" void kernel_launch(void* const* d_in, const int* in_sizes, int n_in,
                              void* d_out, int out_size, void* d_ws, size_t ws_size,
                              hipStream_t stream) {
  const float* x  = (const float*)d_in[0];
  const float* cb = (const float*)d_in[1];

  float* out     = (float*)d_out;
  float* zq      = out;
  float* scalars = out + (size_t)BATCH * DIM;
  float* oidx    = scalars + 5;

  char* wsb = (char*)d_ws;
  ushort* cbh    = (ushort*)(wsb + WS_CBH);
  float*  cbinv  = (float*)(wsb + WS_CBINV);
  float*  xinv   = (float*)(wsb + WS_XINV);
  float*  cval   = (float*)(wsb + WS_CVAL);
  int*    cidx   = (int*)(wsb + WS_CIDX);
  int*    hist   = (int*)(wsb + WS_HIST);
  double* sse    = (double*)(wsb + WS_SSE);

  hipMemsetAsync(hist, 0, NLAT * sizeof(int) + sizeof(double), stream);

  cbnorm_kernel<<<NLAT / 4, 256, 0, stream>>>(cb, cbh, cbinv);
  vq_gemm_kernel<<<256, 256, 0, stream>>>(x, (const uint4*)cbh, xinv, cval, cidx);
  rescore_kernel<<<BATCH / 4, 256, 0, stream>>>(x, cb, xinv, cbinv, cidx,
                                                zq, oidx, hist, sse);
  finalize_kernel<<<1, 256, 0, stream>>>(hist, sse, scalars);
}

// Round 4
// 366.566 us; speedup vs baseline: 3.3071x; 1.2606x over previous
//
#include <hip/hip_runtime.h>
#include <math.h>

#define BATCH 32768
#define DIM   256
#define NLAT  4096

typedef _Float16 f16x8 __attribute__((ext_vector_type(8)));
typedef float    f32x16 __attribute__((ext_vector_type(16)));

// ---------------------------------------------------------------------------
// ws byte offsets (total ~4.23 MB; proven ws_size >= 4.36 MB in round 2)
//   cbh   : fp16 normalized codebook [4096][256]            2 MB
//   cbinv : float [4096]
//   cidx  : int [32768][4 quarters][4] candidate code idxs  2 MB
//   hist  : int [4096]
//   sse   : double
// ---------------------------------------------------------------------------
#define WS_CBH    0u
#define WS_CBINV  2097152u
#define WS_CIDX   2113536u
#define WS_HIST   4210688u
#define WS_SSE    4227072u

// One wave per codebook row: cb_inv + fp16 normalized row.
__global__ __launch_bounds__(256) void cbnorm_kernel(
    const float* __restrict__ cb, ushort* __restrict__ cbh,
    float* __restrict__ cbinv) {
  int w = threadIdx.x >> 6, l = threadIdx.x & 63;
  int row = blockIdx.x * 4 + w;
  const float4* cr = (const float4*)(cb + (size_t)row * DIM);
  float4 v = cr[l];
  float s = v.x * v.x + v.y * v.y + v.z * v.z + v.w * v.w;
  #pragma unroll
  for (int m = 32; m; m >>= 1) s += __shfl_xor(s, m, 64);
  float inv = 1.0f / fmaxf(sqrtf(s), 1e-12f);
  if (l == 0) cbinv[row] = inv;
  union { _Float16 h[4]; uint2 u; } pk;
  pk.h[0] = (_Float16)(v.x * inv);
  pk.h[1] = (_Float16)(v.y * inv);
  pk.h[2] = (_Float16)(v.z * inv);
  pk.h[3] = (_Float16)(v.w * inv);
  ((uint2*)cbh)[row * 64 + l] = pk.u;
}

// MFMA GEMM (codes x batch) + per-row top-4 candidate extraction.
// grid 512: bb = bid>>2 (256 batch rows), q = bid&3 (1024-code quarter).
// Argmax over codes is invariant to positive per-batch-row scaling, so x is
// used UNNORMALIZED here (exact rescore handles normalization). x frags in
// registers; cbh streamed through 2x16KB LDS double-buffer.
__global__ __launch_bounds__(256, 2) void vq_gemm_kernel(
    const float* __restrict__ x, const uint4* __restrict__ cbh4,
    int* __restrict__ cidx) {
  __shared__ __align__(16) char smem[32768];
  char* bufs[2] = { smem, smem + 16384 };

  const int tid = threadIdx.x;
  const int w = tid >> 6, l = tid & 63;
  const int l31 = l & 31, lh = l >> 5;
  const int bb = blockIdx.x >> 2, q = blockIdx.x & 3;
  const int wrow0 = bb * 256 + w * 64;
  const int cbase = q * 1024;

  // ---- x fragments (full K=256) into registers, raw fp16 (no norm) ----
  f16x8 xf[16][2];
  #pragma unroll
  for (int fc = 0; fc < 2; ++fc) {
    const int row = wrow0 + fc * 32 + l31;
    const float4* xr = (const float4*)(x + (size_t)row * DIM);
    #pragma unroll
    for (int s2 = 0; s2 < 16; ++s2) {
      float4 a = xr[s2 * 4 + lh * 2];
      float4 b = xr[s2 * 4 + lh * 2 + 1];
      xf[s2][fc][0] = (_Float16)a.x;
      xf[s2][fc][1] = (_Float16)a.y;
      xf[s2][fc][2] = (_Float16)a.z;
      xf[s2][fc][3] = (_Float16)a.w;
      xf[s2][fc][4] = (_Float16)b.x;
      xf[s2][fc][5] = (_Float16)b.y;
      xf[s2][fc][6] = (_Float16)b.z;
      xf[s2][fc][7] = (_Float16)b.w;
    }
  }

  // ---- staging preamble: buf0 <- (t=0,p=0); pregs <- (t=0,p=1) ----
  uint4 pr[4];
  #pragma unroll
  for (int s = 0; s < 4; ++s) {
    int c = s * 256 + tid;
    pr[s] = cbh4[(cbase + (c >> 4)) * 32 + (c & 15)];
  }
  #pragma unroll
  for (int s = 0; s < 4; ++s) {
    int c = s * 256 + tid; int code = c >> 4; int g = c & 15;
    *(uint4*)(smem + code * 256 + ((g ^ (code & 7)) << 4)) = pr[s];
  }
  #pragma unroll
  for (int s = 0; s < 4; ++s) {
    int c = s * 256 + tid;
    pr[s] = cbh4[(cbase + (c >> 4)) * 32 + 16 + (c & 15)];
  }
  __syncthreads();

  // running top-3 per (lane, fc)
  float tv1[2] = { -3e38f, -3e38f }, tv2[2] = { -3e38f, -3e38f },
        tv3[2] = { -3e38f, -3e38f };
  int   ti1[2] = { 0, 0 }, ti2[2] = { 0, 0 }, ti3[2] = { 0, 0 };

  #pragma unroll 1
  for (int t = 0; t < 16; ++t) {
    f32x16 acc[2][2];
    #pragma unroll
    for (int rf = 0; rf < 2; ++rf)
      #pragma unroll
      for (int fc = 0; fc < 2; ++fc)
        #pragma unroll
        for (int r = 0; r < 16; ++r) acc[rf][fc][r] = 0.f;

    #pragma unroll
    for (int p = 0; p < 2; ++p) {
      // write staged half-tile into the other buffer
      #pragma unroll
      for (int s = 0; s < 4; ++s) {
        int c = s * 256 + tid; int code = c >> 4; int g = c & 15;
        *(uint4*)(bufs[p ^ 1] + code * 256 + ((g ^ (code & 7)) << 4)) = pr[s];
      }
      // prefetch next half-tile
      int tn = (t < 15) ? (t + 1) : 15;
      #pragma unroll
      for (int s = 0; s < 4; ++s) {
        int c = s * 256 + tid;
        pr[s] = cbh4[(cbase + tn * 64 + (c >> 4)) * 32 + p * 16 + (c & 15)];
      }
      // K-loop on bufs[p] (k = 128p .. 128p+127)
      const char* bp = bufs[p];
      #pragma unroll
      for (int s = 0; s < 8; ++s) {
        f16x8 af[2];
        #pragma unroll
        for (int rf = 0; rf < 2; ++rf) {
          int m = rf * 32 + l31;
          int g = 2 * s + lh;
          af[rf] = *(const f16x8*)(bp + m * 256 + ((g ^ (m & 7)) << 4));
        }
        #pragma unroll
        for (int rf = 0; rf < 2; ++rf)
          #pragma unroll
          for (int fc = 0; fc < 2; ++fc)
            acc[rf][fc] = __builtin_amdgcn_mfma_f32_32x32x16_f16(
                af[rf], xf[p * 8 + s][fc], acc[rf][fc], 0, 0, 0);
      }
      __syncthreads();
    }

    // top-3 update for this 64-code tile
    #pragma unroll
    for (int fc = 0; fc < 2; ++fc) {
      float m = acc[0][fc][0];
      #pragma unroll
      for (int rf = 0; rf < 2; ++rf)
        #pragma unroll
        for (int r = 0; r < 16; ++r) m = fmaxf(m, acc[rf][fc][r]);
      if (m > tv3[fc]) {   // rare after early tiles
        #pragma unroll
        for (int rf = 0; rf < 2; ++rf)
          #pragma unroll
          for (int r = 0; r < 16; ++r) {
            float v = acc[rf][fc][r];
            if (v > tv3[fc]) {
              int code = cbase + t * 64 + rf * 32 + (r & 3) + 8 * (r >> 2) + 4 * lh;
              if (v > tv1[fc]) {
                tv3[fc] = tv2[fc]; ti3[fc] = ti2[fc];
                tv2[fc] = tv1[fc]; ti2[fc] = ti1[fc];
                tv1[fc] = v;       ti1[fc] = code;
              } else if (v > tv2[fc]) {
                tv3[fc] = tv2[fc]; ti3[fc] = ti2[fc];
                tv2[fc] = v;       ti2[fc] = code;
              } else {
                tv3[fc] = v;       ti3[fc] = code;
              }
            }
          }
      }
    }
  }

  // ---- merge lane pair (l, l^32) -> per-(row,quarter) top-4 ----
  #pragma unroll
  for (int fc = 0; fc < 2; ++fc) {
    float pv[6]; int pi[6];
    pv[0] = tv1[fc]; pv[1] = tv2[fc]; pv[2] = tv3[fc];
    pi[0] = ti1[fc]; pi[1] = ti2[fc]; pi[2] = ti3[fc];
    #pragma unroll
    for (int k = 0; k < 3; ++k) {
      pv[3 + k] = __shfl_xor(pv[k], 32, 64);
      pi[3 + k] = __shfl_xor(pi[k], 32, 64);
    }
    if (lh == 0) {
      float bv[4] = { -3e38f, -3e38f, -3e38f, -3e38f };
      int   bi[4] = { 0x7fffffff, 0x7fffffff, 0x7fffffff, 0x7fffffff };
      #pragma unroll
      for (int e = 0; e < 6; ++e) {
        float v = pv[e]; int ci = pi[e];
        #pragma unroll
        for (int k = 0; k < 4; ++k) {
          bool better = (v > bv[k]) || (v == bv[k] && ci < bi[k]);
          if (better) {
            float tvv = bv[k]; int tci = bi[k];
            bv[k] = v; bi[k] = ci;
            v = tvv; ci = tci;
          }
        }
      }
      int row = wrow0 + fc * 32 + l31;
      #pragma unroll
      for (int k = 0; k < 4; ++k)
        cidx[row * 16 + q * 4 + k] = bi[k];
    }
  }
}

// Exact fp32 rescore of 16 candidates/row (4 lanes per candidate, all
// concurrent), inline x row-norm, + all per-row outputs.
__global__ __launch_bounds__(256) void rescore_kernel(
    const float* __restrict__ x, const float* __restrict__ cb,
    const float* __restrict__ cbinv, const int* __restrict__ cidx,
    float* __restrict__ zq, float* __restrict__ out_idx,
    int* __restrict__ hist, double* __restrict__ sse) {
  __shared__ float4 xs[4][68];     // +4 pad: conflict-free 4-group reads
  __shared__ float part[4];
  int tid = threadIdx.x, w = tid >> 6, l = tid & 63;
  int row = blockIdx.x * 4 + w;
  const float4* xr = (const float4*)(x + (size_t)row * DIM);
  float4 xv = xr[l];
  xs[w][l + (l >> 4)] = xv;
  // inline row norm (round-1-proven formula)
  float s0 = xv.x * xv.x + xv.y * xv.y + xv.z * xv.z + xv.w * xv.w;
  #pragma unroll
  for (int m = 32; m; m >>= 1) s0 += __shfl_xor(s0, m, 64);
  float xinv = 1.0f / fmaxf(sqrtf(s0), 1e-12f);

  int cand = l >> 2, j = l & 3;          // candidate, 64-dim chunk
  int ci = cidx[row * 16 + cand] & (NLAT - 1);   // defensive clamp
  float cbi = cbinv[ci];
  const float4* cr = (const float4*)(cb + (size_t)ci * DIM);
  __syncthreads();                       // xs visible
  float d = 0.f;
  #pragma unroll
  for (int i = 0; i < 16; ++i) {
    float4 a = xs[w][j * 17 + i];
    float4 c = cr[j * 16 + i];
    d += (a.x * xinv) * (c.x * cbi) + (a.y * xinv) * (c.y * cbi)
       + (a.z * xinv) * (c.z * cbi) + (a.w * xinv) * (c.w * cbi);
  }
  d += __shfl_xor(d, 1, 64);
  d += __shfl_xor(d, 2, 64);             // all 4 lanes hold candidate's dot
  float bestv = -3e38f; int besti = 0x7fffffff;
  #pragma unroll
  for (int c = 0; c < 16; ++c) {
    float v  = __shfl(d, c * 4, 64);
    int   vc = __shfl(ci, c * 4, 64);
    bool better = (v > bestv) || (v == bestv && vc < besti);
    bestv = better ? v : bestv;
    besti = better ? vc : besti;
  }
  // outputs
  float4 zv = ((const float4*)(cb + (size_t)besti * DIM))[l];
  float4 o;
  o.x = xv.x + (zv.x - xv.x); o.y = xv.y + (zv.y - xv.y);
  o.z = xv.z + (zv.z - xv.z); o.w = xv.w + (zv.w - xv.w);
  ((float4*)(zq + (size_t)row * DIM))[l] = o;
  float dx = xv.x - zv.x, dy = xv.y - zv.y, dz = xv.z - zv.z, dw = xv.w - zv.w;
  float s = dx * dx + dy * dy + dz * dz + dw * dw;
  #pragma unroll
  for (int m = 32; m; m >>= 1) s += __shfl_xor(s, m, 64);
  if (l == 0) part[w] = s;
  __syncthreads();
  if (tid == 0)
    atomicAdd(sse, (double)((part[0] + part[1]) + (part[2] + part[3])));
  if (l == 0) {
    atomicAdd(&hist[besti], 1);
    out_idx[row] = (float)besti;
  }
}

// Entropy from histogram + final scalar losses.
__global__ __launch_bounds__(256) void finalize_kernel(
    const int* __restrict__ hist, const double* __restrict__ sse,
    float* __restrict__ outs) {
  int tid = threadIdx.x;
  double s = 0.0;
  for (int k = tid; k < NLAT; k += 256) {
    int c = hist[k];
    if (c > 0) {
      float p = (float)c * (1.0f / 32768.0f);
      s += (double)(p * logf(p));
    }
  }
  #pragma unroll
  for (int off = 32; off; off >>= 1) s += __shfl_xor(s, off, 64);
  __shared__ double part[4];
  int w = tid >> 6, l = tid & 63;
  if (l == 0) part[w] = s;
  __syncthreads();
  if (tid == 0) {
    double H = -((part[0] + part[1]) + (part[2] + part[3]));
    double qv = sse[0] * (1.0 / ((double)BATCH * (double)DIM));
    float qf = (float)qv;
    float Hf = (float)H;
    float ent_loss = -Hf;
    float vq = qf + 0.25f * qf + 0.1f * ent_loss;
    outs[0] = vq;
    outs[1] = qf;
    outs[2] = qf;
    outs[3] = ent_loss;
    outs[4] = Hf;
  }
}

extern "C" void kernel_launch(void* const* d_in, const int* in_sizes, int n_in,
                              void* d_out, int out_size, void* d_ws, size_t ws_size,
                              hipStream_t stream) {
  const float* x  = (const float*)d_in[0];
  const float* cb = (const float*)d_in[1];

  float* out     = (float*)d_out;
  float* zq      = out;
  float* scalars = out + (size_t)BATCH * DIM;
  float* oidx    = scalars + 5;

  char* wsb = (char*)d_ws;
  ushort* cbh   = (ushort*)(wsb + WS_CBH);
  float*  cbinv = (float*)(wsb + WS_CBINV);
  int*    cidx  = (int*)(wsb + WS_CIDX);
  int*    hist  = (int*)(wsb + WS_HIST);
  double* sse   = (double*)(wsb + WS_SSE);

  hipMemsetAsync(hist, 0, NLAT * sizeof(int) + sizeof(double), stream);

  cbnorm_kernel<<<NLAT / 4, 256, 0, stream>>>(cb, cbh, cbinv);
  vq_gemm_kernel<<<512, 256, 0, stream>>>(x, (const uint4*)cbh, cidx);
  rescore_kernel<<<BATCH / 4, 256, 0, stream>>>(x, cb, cbinv, cidx,
                                                zq, oidx, hist, sse);
  finalize_kernel<<<1, 256, 0, stream>>>(hist, sse, scalars);
}

// Round 5
// 359.374 us; speedup vs baseline: 3.3733x; 1.0200x over previous
//
#include <hip/hip_runtime.h>
#include <math.h>

#define BATCH 32768
#define DIM   256
#define NLAT  4096

typedef _Float16 f16x8 __attribute__((ext_vector_type(8)));
typedef float    f32x16 __attribute__((ext_vector_type(16)));

// ---------------------------------------------------------------------------
// ws byte offsets (total ~4.23 MB; proven budget from rounds 2/4)
//   cbh   : fp16 normalized codebook [4096][256]            2 MB
//   cbinv : float [4096]
//   keys  : uint [32768][16]  packed (approx val | idx)     2 MB
//   hist  : int [4096]
//   sse   : double
// ---------------------------------------------------------------------------
#define WS_CBH    0u
#define WS_CBINV  2097152u
#define WS_KEYS   2113536u
#define WS_HIST   4210688u
#define WS_SSE    4227072u

// Order-preserving float->uint, top 20 bits kept, low 12 bits = code idx.
// Truncation is a floor in ordered space (decoded <= value, err <= 2^-12 rel).
__device__ inline uint kenc(float v, int idx) {
  uint b = __float_as_uint(v);
  uint o = (b & 0x80000000u) ? ~b : (b ^ 0x80000000u);
  return (o & 0xFFFFF000u) | (uint)idx;
}
__device__ inline float kdec(uint key) {
  uint u = key & 0xFFFFF000u;
  uint bits = (u & 0x80000000u) ? (u ^ 0x80000000u) : ~u;
  return __uint_as_float(bits);
}

// One wave per codebook row: cb_inv + fp16 normalized row.
__global__ __launch_bounds__(256) void cbnorm_kernel(
    const float* __restrict__ cb, ushort* __restrict__ cbh,
    float* __restrict__ cbinv) {
  int w = threadIdx.x >> 6, l = threadIdx.x & 63;
  int row = blockIdx.x * 4 + w;
  const float4* cr = (const float4*)(cb + (size_t)row * DIM);
  float4 v = cr[l];
  float s = v.x * v.x + v.y * v.y + v.z * v.z + v.w * v.w;
  #pragma unroll
  for (int m = 32; m; m >>= 1) s += __shfl_xor(s, m, 64);
  float inv = 1.0f / fmaxf(sqrtf(s), 1e-12f);
  if (l == 0) cbinv[row] = inv;
  union { _Float16 h[4]; uint2 u; } pk;
  pk.h[0] = (_Float16)(v.x * inv);
  pk.h[1] = (_Float16)(v.y * inv);
  pk.h[2] = (_Float16)(v.z * inv);
  pk.h[3] = (_Float16)(v.w * inv);
  ((uint2*)cbh)[row * 64 + l] = pk.u;
}

// MFMA GEMM (codes x batch) + per-row top-4 candidate extraction (as keys).
// grid 512: bb = bid>>2 (256 batch rows), q = bid&3 (1024-code quarter).
// x used UNNORMALIZED (argmax invariant to positive per-row scale).
__global__ __launch_bounds__(256, 2) void vq_gemm_kernel(
    const float* __restrict__ x, const uint4* __restrict__ cbh4,
    uint* __restrict__ keys) {
  __shared__ __align__(16) char smem[32768];
  char* bufs[2] = { smem, smem + 16384 };

  const int tid = threadIdx.x;
  const int w = tid >> 6, l = tid & 63;
  const int l31 = l & 31, lh = l >> 5;
  const int bb = blockIdx.x >> 2, q = blockIdx.x & 3;
  const int wrow0 = bb * 256 + w * 64;
  const int cbase = q * 1024;

  // ---- x fragments (full K=256) into registers, raw fp16 (no norm) ----
  f16x8 xf[16][2];
  #pragma unroll
  for (int fc = 0; fc < 2; ++fc) {
    const int row = wrow0 + fc * 32 + l31;
    const float4* xr = (const float4*)(x + (size_t)row * DIM);
    #pragma unroll
    for (int s2 = 0; s2 < 16; ++s2) {
      float4 a = xr[s2 * 4 + lh * 2];
      float4 b = xr[s2 * 4 + lh * 2 + 1];
      xf[s2][fc][0] = (_Float16)a.x;
      xf[s2][fc][1] = (_Float16)a.y;
      xf[s2][fc][2] = (_Float16)a.z;
      xf[s2][fc][3] = (_Float16)a.w;
      xf[s2][fc][4] = (_Float16)b.x;
      xf[s2][fc][5] = (_Float16)b.y;
      xf[s2][fc][6] = (_Float16)b.z;
      xf[s2][fc][7] = (_Float16)b.w;
    }
  }

  // ---- staging preamble: buf0 <- (t=0,p=0); pregs <- (t=0,p=1) ----
  uint4 pr[4];
  #pragma unroll
  for (int s = 0; s < 4; ++s) {
    int c = s * 256 + tid;
    pr[s] = cbh4[(cbase + (c >> 4)) * 32 + (c & 15)];
  }
  #pragma unroll
  for (int s = 0; s < 4; ++s) {
    int c = s * 256 + tid; int code = c >> 4; int g = c & 15;
    *(uint4*)(smem + code * 256 + ((g ^ (code & 7)) << 4)) = pr[s];
  }
  #pragma unroll
  for (int s = 0; s < 4; ++s) {
    int c = s * 256 + tid;
    pr[s] = cbh4[(cbase + (c >> 4)) * 32 + 16 + (c & 15)];
  }
  __syncthreads();

  // running top-3 per (lane, fc)
  float tv1[2] = { -3e38f, -3e38f }, tv2[2] = { -3e38f, -3e38f },
        tv3[2] = { -3e38f, -3e38f };
  int   ti1[2] = { 0, 0 }, ti2[2] = { 0, 0 }, ti3[2] = { 0, 0 };

  #pragma unroll 1
  for (int t = 0; t < 16; ++t) {
    f32x16 acc[2][2];
    #pragma unroll
    for (int rf = 0; rf < 2; ++rf)
      #pragma unroll
      for (int fc = 0; fc < 2; ++fc)
        #pragma unroll
        for (int r = 0; r < 16; ++r) acc[rf][fc][r] = 0.f;

    #pragma unroll
    for (int p = 0; p < 2; ++p) {
      // write staged half-tile into the other buffer
      #pragma unroll
      for (int s = 0; s < 4; ++s) {
        int c = s * 256 + tid; int code = c >> 4; int g = c & 15;
        *(uint4*)(bufs[p ^ 1] + code * 256 + ((g ^ (code & 7)) << 4)) = pr[s];
      }
      // prefetch next half-tile
      int tn = (t < 15) ? (t + 1) : 15;
      #pragma unroll
      for (int s = 0; s < 4; ++s) {
        int c = s * 256 + tid;
        pr[s] = cbh4[(cbase + tn * 64 + (c >> 4)) * 32 + p * 16 + (c & 15)];
      }
      // K-loop on bufs[p] (k = 128p .. 128p+127)
      const char* bp = bufs[p];
      #pragma unroll
      for (int s = 0; s < 8; ++s) {
        f16x8 af[2];
        #pragma unroll
        for (int rf = 0; rf < 2; ++rf) {
          int m = rf * 32 + l31;
          int g = 2 * s + lh;
          af[rf] = *(const f16x8*)(bp + m * 256 + ((g ^ (m & 7)) << 4));
        }
        #pragma unroll
        for (int rf = 0; rf < 2; ++rf)
          #pragma unroll
          for (int fc = 0; fc < 2; ++fc)
            acc[rf][fc] = __builtin_amdgcn_mfma_f32_32x32x16_f16(
                af[rf], xf[p * 8 + s][fc], acc[rf][fc], 0, 0, 0);
      }
      __syncthreads();
    }

    // top-3 update for this 64-code tile
    #pragma unroll
    for (int fc = 0; fc < 2; ++fc) {
      float m = acc[0][fc][0];
      #pragma unroll
      for (int rf = 0; rf < 2; ++rf)
        #pragma unroll
        for (int r = 0; r < 16; ++r) m = fmaxf(m, acc[rf][fc][r]);
      if (m > tv3[fc]) {   // rare after early tiles
        #pragma unroll
        for (int rf = 0; rf < 2; ++rf)
          #pragma unroll
          for (int r = 0; r < 16; ++r) {
            float v = acc[rf][fc][r];
            if (v > tv3[fc]) {
              int code = cbase + t * 64 + rf * 32 + (r & 3) + 8 * (r >> 2) + 4 * lh;
              if (v > tv1[fc]) {
                tv3[fc] = tv2[fc]; ti3[fc] = ti2[fc];
                tv2[fc] = tv1[fc]; ti2[fc] = ti1[fc];
                tv1[fc] = v;       ti1[fc] = code;
              } else if (v > tv2[fc]) {
                tv3[fc] = tv2[fc]; ti3[fc] = ti2[fc];
                tv2[fc] = v;       ti2[fc] = code;
              } else {
                tv3[fc] = v;       ti3[fc] = code;
              }
            }
          }
      }
    }
  }

  // ---- merge lane pair (l, l^32) -> per-(row,quarter) top-4 keys ----
  #pragma unroll
  for (int fc = 0; fc < 2; ++fc) {
    float pv[6]; int pi[6];
    pv[0] = tv1[fc]; pv[1] = tv2[fc]; pv[2] = tv3[fc];
    pi[0] = ti1[fc]; pi[1] = ti2[fc]; pi[2] = ti3[fc];
    #pragma unroll
    for (int k = 0; k < 3; ++k) {
      pv[3 + k] = __shfl_xor(pv[k], 32, 64);
      pi[3 + k] = __shfl_xor(pi[k], 32, 64);
    }
    if (lh == 0) {
      float bv[4] = { -3e38f, -3e38f, -3e38f, -3e38f };
      int   bi[4] = { 0x7fffffff, 0x7fffffff, 0x7fffffff, 0x7fffffff };
      #pragma unroll
      for (int e = 0; e < 6; ++e) {
        float v = pv[e]; int ci = pi[e];
        #pragma unroll
        for (int k = 0; k < 4; ++k) {
          bool better = (v > bv[k]) || (v == bv[k] && ci < bi[k]);
          if (better) {
            float tvv = bv[k]; int tci = bi[k];
            bv[k] = v; bi[k] = ci;
            v = tvv; ci = tci;
          }
        }
      }
      int row = wrow0 + fc * 32 + l31;
      #pragma unroll
      for (int k = 0; k < 4; ++k)
        keys[row * 16 + q * 4 + k] = kenc(bv[k], bi[k] & (NLAT - 1));
    }
  }
}

// Screened rescore: decode 16 candidate keys, exact-rescore only those
// within the rigorous fp16-error window (usually none beyond the max).
// One wave per row; all loads fully coalesced.
__global__ __launch_bounds__(256) void rescore_kernel(
    const float* __restrict__ x, const float* __restrict__ cb,
    const float* __restrict__ cbinv, const uint* __restrict__ keys,
    float* __restrict__ zq, float* __restrict__ out_idx,
    int* __restrict__ hist, double* __restrict__ sse) {
  __shared__ float part[4];
  int tid = threadIdx.x, w = tid >> 6, l = tid & 63;
  int row = blockIdx.x * 4 + w;
  const float4* xr = (const float4*)(x + (size_t)row * DIM);
  float4 xv = xr[l];
  float s0 = xv.x * xv.x + xv.y * xv.y + xv.z * xv.z + xv.w * xv.w;
  #pragma unroll
  for (int m = 32; m; m >>= 1) s0 += __shfl_xor(s0, m, 64);
  float xnorm = sqrtf(s0);
  float xinv = 1.0f / fmaxf(xnorm, 1e-12f);

  // 16 keys replicated over the 4 16-lane groups
  uint key = keys[row * 16 + (l & 15)];
  uint kmax = key;
  #pragma unroll
  for (int m = 1; m < 16; m <<= 1) {
    uint o = __shfl_xor(kmax, m, 64);
    kmax = (o > kmax) ? o : kmax;
  }
  float dmax = kdec(kmax);
  // E: rigorous bound 1.02e-3*||x|| (fp16 quantization, exact fp32 products)
  // + 7.3e-5*||x|| key truncation; 3e-3 gives ~2.7x margin.
  float thr = dmax - 2.0f * (3e-3f * xnorm);
  bool inwin = (kdec(key) >= thr) && (l < 16);
  unsigned long long mask = __ballot(inwin);
  int besti;
  if (__popcll(mask) == 1) {
    besti = (int)(kmax & 0xFFFu);       // provably the exact argmax
  } else {
    float bestv = -3e38f; besti = 0x7fffffff;
    unsigned long long mm = mask;
    while (mm) {
      int b = __ffsll(mm) - 1; mm &= mm - 1;
      int ci = (int)(__shfl(key, b, 64) & 0xFFFu);
      float cbi = cbinv[ci];
      const float4* cr = (const float4*)(cb + (size_t)ci * DIM);
      float4 cv = cr[l];
      float d = (xv.x * xinv) * (cv.x * cbi) + (xv.y * xinv) * (cv.y * cbi)
              + (xv.z * xinv) * (cv.z * cbi) + (xv.w * xinv) * (cv.w * cbi);
      #pragma unroll
      for (int m = 32; m; m >>= 1) d += __shfl_xor(d, m, 64);
      bool better = (d > bestv) || (d == bestv && ci < besti);
      bestv = better ? d : bestv;
      besti = better ? ci : besti;
    }
  }

  // outputs
  float4 zv = ((const float4*)(cb + (size_t)besti * DIM))[l];
  float4 o;
  o.x = xv.x + (zv.x - xv.x); o.y = xv.y + (zv.y - xv.y);
  o.z = xv.z + (zv.z - xv.z); o.w = xv.w + (zv.w - xv.w);
  ((float4*)(zq + (size_t)row * DIM))[l] = o;
  float dx = xv.x - zv.x, dy = xv.y - zv.y, dz = xv.z - zv.z, dw = xv.w - zv.w;
  float s = dx * dx + dy * dy + dz * dz + dw * dw;
  #pragma unroll
  for (int m = 32; m; m >>= 1) s += __shfl_xor(s, m, 64);
  if (l == 0) part[w] = s;
  __syncthreads();
  if (tid == 0)
    atomicAdd(sse, (double)((part[0] + part[1]) + (part[2] + part[3])));
  if (l == 0) {
    atomicAdd(&hist[besti], 1);
    out_idx[row] = (float)besti;
  }
}

// Entropy from histogram + final scalar losses.
__global__ __launch_bounds__(256) void finalize_kernel(
    const int* __restrict__ hist, const double* __restrict__ sse,
    float* __restrict__ outs) {
  int tid = threadIdx.x;
  double s = 0.0;
  for (int k = tid; k < NLAT; k += 256) {
    int c = hist[k];
    if (c > 0) {
      float p = (float)c * (1.0f / 32768.0f);
      s += (double)(p * logf(p));
    }
  }
  #pragma unroll
  for (int off = 32; off; off >>= 1) s += __shfl_xor(s, off, 64);
  __shared__ double part[4];
  int w = tid >> 6, l = tid & 63;
  if (l == 0) part[w] = s;
  __syncthreads();
  if (tid == 0) {
    double H = -((part[0] + part[1]) + (part[2] + part[3]));
    double qv = sse[0] * (1.0 / ((double)BATCH * (double)DIM));
    float qf = (float)qv;
    float Hf = (float)H;
    float ent_loss = -Hf;
    float vq = qf + 0.25f * qf + 0.1f * ent_loss;
    outs[0] = vq;
    outs[1] = qf;
    outs[2] = qf;
    outs[3] = ent_loss;
    outs[4] = Hf;
  }
}

extern "C" void kernel_launch(void* const* d_in, const int* in_sizes, int n_in,
                              void* d_out, int out_size, void* d_ws, size_t ws_size,
                              hipStream_t stream) {
  const float* x  = (const float*)d_in[0];
  const float* cb = (const float*)d_in[1];

  float* out     = (float*)d_out;
  float* zq      = out;
  float* scalars = out + (size_t)BATCH * DIM;
  float* oidx    = scalars + 5;

  char* wsb = (char*)d_ws;
  ushort* cbh   = (ushort*)(wsb + WS_CBH);
  float*  cbinv = (float*)(wsb + WS_CBINV);
  uint*   keys  = (uint*)(wsb + WS_KEYS);
  int*    hist  = (int*)(wsb + WS_HIST);
  double* sse   = (double*)(wsb + WS_SSE);

  hipMemsetAsync(hist, 0, NLAT * sizeof(int) + sizeof(double), stream);

  cbnorm_kernel<<<NLAT / 4, 256, 0, stream>>>(cb, cbh, cbinv);
  vq_gemm_kernel<<<512, 256, 0, stream>>>(x, (const uint4*)cbh, keys);
  rescore_kernel<<<BATCH / 4, 256, 0, stream>>>(x, cb, cbinv, keys,
                                                zq, oidx, hist, sse);
  finalize_kernel<<<1, 256, 0, stream>>>(hist, sse, scalars);
}